// Round 1
// baseline (684.256 us; speedup 1.0000x reference)
//
#include <hip/hip_runtime.h>
#include <stdint.h>

#define IDIM 2048
#define ODIM 1024
#define NACT 64
#define NB 1024
#define NT 16

typedef __attribute__((ext_vector_type(8))) short short8;
typedef __attribute__((ext_vector_type(4))) float floatx4;

__device__ __forceinline__ unsigned short f2bf(float f) {
    union { float f; unsigned u; } v; v.f = f;
    unsigned r = v.u + 0x7FFFu + ((v.u >> 16) & 1u);
    return (unsigned short)(r >> 16);
}

__device__ __forceinline__ short8 pack_bf8(float4 a, float4 b) {
    short8 r;
    r[0] = (short)f2bf(a.x); r[1] = (short)f2bf(a.y);
    r[2] = (short)f2bf(a.z); r[3] = (short)f2bf(a.w);
    r[4] = (short)f2bf(b.x); r[5] = (short)f2bf(b.y);
    r[6] = (short)f2bf(b.z); r[7] = (short)f2bf(b.w);
    return r;
}

// ---- temporal mean over T, output bf16 ----
__global__ __launch_bounds__(256) void k_avg(const float* __restrict__ p,
                                             const float* __restrict__ e,
                                             unsigned short* __restrict__ pavg,
                                             unsigned short* __restrict__ eavg) {
    int idx = blockIdx.x * 256 + threadIdx.x;   // 0 .. NB*IDIM/4-1
    int b  = idx >> 9;                          // IDIM/4 = 512 float4 per row
    int d4 = idx & 511;
    const float4* pr = (const float4*)(p + (size_t)b * (NT * IDIM)) + d4;
    const float4* er = (const float4*)(e + (size_t)b * (NT * IDIM)) + d4;
    float sx=0, sy=0, sz=0, sw=0, tx=0, ty=0, tz=0, tw=0;
#pragma unroll
    for (int t = 0; t < NT; ++t) {
        float4 a = pr[t * (IDIM/4)];
        float4 c = er[t * (IDIM/4)];
        sx += a.x; sy += a.y; sz += a.z; sw += a.w;
        tx += c.x; ty += c.y; tz += c.z; tw += c.w;
    }
    const float s = 1.0f / NT;
    ushort4 op = make_ushort4(f2bf(sx*s), f2bf(sy*s), f2bf(sz*s), f2bf(sw*s));
    ushort4 oe = make_ushort4(f2bf(tx*s), f2bf(ty*s), f2bf(tz*s), f2bf(tw*s));
    *(ushort4*)(pavg + (size_t)b*IDIM + d4*4) = op;
    *(ushort4*)(eavg + (size_t)b*IDIM + d4*4) = oe;
}

// ---- f32 -> bf16 convert, both weight matrices in one launch ----
__global__ __launch_bounds__(256) void k_cvt(const float* __restrict__ wp,
                                             const float* __restrict__ we,
                                             unsigned short* __restrict__ op,
                                             unsigned short* __restrict__ oe) {
    int idx = blockIdx.x * 256 + threadIdx.x;   // over float4s of both matrices
    const float4* src; unsigned short* dst; int j;
    if (idx < (ODIM*IDIM/4)) { src = (const float4*)wp; dst = op; j = idx; }
    else                     { src = (const float4*)we; dst = oe; j = idx - (ODIM*IDIM/4); }
    float4 v = src[j];
    *(ushort4*)(dst + (size_t)j*4) = make_ushort4(f2bf(v.x), f2bf(v.y), f2bf(v.z), f2bf(v.w));
}

// ---- bucket batch rows by action ----
__global__ void k_group(const int* __restrict__ action,
                        int* __restrict__ order, int* __restrict__ starts) {
    __shared__ int cnt[NACT], cnt2[NACT], base[NACT];
    int t = threadIdx.x;
    if (t < NACT) { cnt[t] = 0; cnt2[t] = 0; }
    __syncthreads();
    int a = action[t];
    atomicAdd(&cnt[a], 1);
    __syncthreads();
    if (t < NACT) {
        int s = 0;
        for (int j = 0; j < t; ++j) s += cnt[j];
        base[t] = s;
        starts[t] = s;
        if (t == NACT - 1) starts[NACT] = s + cnt[t];
    }
    __syncthreads();
    int pos = base[a] + atomicAdd(&cnt2[a], 1);
    order[pos] = t;
}

// ---- embed GEMM: C[b][d] = sum_k avg[b][k]*W[d][k] + bias[d] ----
// Barrier-free fragment streaming. Block = 4 waves; wave w owns rows
// [row0+w*32, +32) x cols [col0, col0+64). A/B fragments loaded directly
// from global (16B per lane per fragment: lane l -> row/col (l&15),
// k = (l>>4)*8 .. +7), no LDS, no __syncthreads.
__global__ __launch_bounds__(256) void k_embed(const unsigned short* __restrict__ pavg,
                                               const unsigned short* __restrict__ eavg,
                                               const unsigned short* __restrict__ wpb,
                                               const unsigned short* __restrict__ web,
                                               const float* __restrict__ bp,
                                               const float* __restrict__ be,
                                               unsigned short* __restrict__ peb,
                                               float* __restrict__ eout) {
    const int z = blockIdx.z;
    const unsigned short* Ag = z ? eavg : pavg;
    const unsigned short* Wg = z ? web  : wpb;
    const float* bias        = z ? be   : bp;
    const int row0 = blockIdx.x * 128;
    const int col0 = blockIdx.y * 64;
    const int tid  = threadIdx.x;
    const int w    = tid >> 6, lane = tid & 63;
    const int lr   = lane & 15, quad = lane >> 4;

    const unsigned short* a0p = Ag + (size_t)(row0 + w*32 + lr) * IDIM + quad*8;
    const unsigned short* a1p = a0p + (size_t)16 * IDIM;
    const unsigned short* bq  = Wg + quad*8;

    floatx4 acc[2][4];
#pragma unroll
    for (int s = 0; s < 2; ++s)
#pragma unroll
        for (int t = 0; t < 4; ++t) { floatx4 zz = {0.f,0.f,0.f,0.f}; acc[s][t] = zz; }

#pragma unroll 2
    for (int ks = 0; ks < IDIM/32; ++ks) {
        const int k0 = ks * 32;
        short8 af0 = *(const short8*)(a0p + k0);
        short8 af1 = *(const short8*)(a1p + k0);
        short8 bf[4];
#pragma unroll
        for (int t = 0; t < 4; ++t)
            bf[t] = *(const short8*)(bq + (size_t)(col0 + t*16 + lr)*IDIM + k0);
#pragma unroll
        for (int t = 0; t < 4; ++t) {
            acc[0][t] = __builtin_amdgcn_mfma_f32_16x16x32_bf16(af0, bf[t], acc[0][t], 0, 0, 0);
            acc[1][t] = __builtin_amdgcn_mfma_f32_16x16x32_bf16(af1, bf[t], acc[1][t], 0, 0, 0);
        }
    }

#pragma unroll
    for (int s = 0; s < 2; ++s) {
        const int rg = row0 + w*32 + s*16 + quad*4;
#pragma unroll
        for (int t = 0; t < 4; ++t) {
            const int cg = col0 + t*16 + lr;
            const float bv = bias[cg];
#pragma unroll
            for (int r = 0; r < 4; ++r) {
                float val = acc[s][t][r] + bv;
                if (z) eout[(size_t)(rg + r)*ODIM + cg] = val;
                else   peb[(size_t)(rg + r)*ODIM + cg] = f2bf(val);
            }
        }
    }
}

// ---- grouped transform: p_t[b][i] = sum_j Wt[a][i][j] * p_embed[b][j] ----
// Barrier-free, LDS-free. Block = 4 waves; wave w owns i-rows
// [i0+w*32, +32) x up to 32 b-cols of one action chunk. M fragments are
// 8 consecutive f32 per lane (32B), converted to bf16 in-register; each
// W_trans element is loaded exactly once chip-wide -> pure 268 MB stream.
// P fragments (bf16) come straight from peb (L2-hot).
__global__ __launch_bounds__(256) void k_trans(const float* __restrict__ Wt,
                                               const unsigned short* __restrict__ peb,
                                               const int* __restrict__ order,
                                               const int* __restrict__ starts,
                                               float* __restrict__ out) {
    const int a  = blockIdx.z;
    const int g0 = starts[a], g1 = starts[a+1];
    const int gs = g0 + blockIdx.y * 32;
    int nb = g1 - gs;
    if (nb <= 0) return;
    if (nb > 32) nb = 32;
    const int i0 = blockIdx.x * 128;
    const int tid = threadIdx.x;
    const int w  = tid >> 6, lane = tid & 63;
    const int lr = lane & 15, quad = lane >> 4;

    const float* M  = Wt + (size_t)a * ODIM * ODIM;
    const float* m0 = M + (size_t)(i0 + w*32 + lr) * ODIM + quad*8;
    const float* m1 = m0 + (size_t)16 * ODIM;

    const int c0 = lr, c1 = 16 + lr;
    const int b0 = order[gs + (c0 < nb ? c0 : 0)];
    const int b1 = order[gs + (c1 < nb ? c1 : 0)];
    const unsigned short* p0 = peb + (size_t)b0 * ODIM + quad*8;
    const unsigned short* p1 = peb + (size_t)b1 * ODIM + quad*8;

    floatx4 acc[2][2];
#pragma unroll
    for (int s = 0; s < 2; ++s)
#pragma unroll
        for (int t = 0; t < 2; ++t) { floatx4 zz = {0.f,0.f,0.f,0.f}; acc[s][t] = zz; }

#pragma unroll 2
    for (int ks = 0; ks < ODIM/32; ++ks) {
        const int k0 = ks * 32;
        float4 xa = *(const float4*)(m0 + k0);
        float4 xb = *(const float4*)(m0 + k0 + 4);
        float4 ya = *(const float4*)(m1 + k0);
        float4 yb = *(const float4*)(m1 + k0 + 4);
        short8 pf0 = *(const short8*)(p0 + k0);
        short8 pf1 = *(const short8*)(p1 + k0);
        short8 af0 = pack_bf8(xa, xb);
        short8 af1 = pack_bf8(ya, yb);
        acc[0][0] = __builtin_amdgcn_mfma_f32_16x16x32_bf16(af0, pf0, acc[0][0], 0, 0, 0);
        acc[0][1] = __builtin_amdgcn_mfma_f32_16x16x32_bf16(af0, pf1, acc[0][1], 0, 0, 0);
        acc[1][0] = __builtin_amdgcn_mfma_f32_16x16x32_bf16(af1, pf0, acc[1][0], 0, 0, 0);
        acc[1][1] = __builtin_amdgcn_mfma_f32_16x16x32_bf16(af1, pf1, acc[1][1], 0, 0, 0);
    }

#pragma unroll
    for (int t = 0; t < 2; ++t) {
        int bb = t*16 + lr;
        if (bb < nb) {
            int bg = t ? b1 : b0;
#pragma unroll
            for (int s = 0; s < 2; ++s) {
                int ig = i0 + w*32 + s*16 + quad*4;   // 4 acc regs = consecutive i
                float4 v = make_float4(acc[s][t][0], acc[s][t][1], acc[s][t][2], acc[s][t][3]);
                *(float4*)(out + (size_t)bg*ODIM + ig) = v;
            }
        }
    }
}

extern "C" void kernel_launch(void* const* d_in, const int* in_sizes, int n_in,
                              void* d_out, int out_size, void* d_ws, size_t ws_size,
                              hipStream_t stream) {
    const float* prec = (const float*)d_in[0];
    const float* eff  = (const float*)d_in[1];
    const int*   act  = (const int*)d_in[2];
    const float* Wp   = (const float*)d_in[3];
    const float* bp   = (const float*)d_in[4];
    const float* We   = (const float*)d_in[5];
    const float* be   = (const float*)d_in[6];
    const float* Wt   = (const float*)d_in[7];
    float* out = (float*)d_out;                // [0,1048576): p_transformed, then e_embed

    uint8_t* ws = (uint8_t*)d_ws;              // needs ~18.9 MB
    unsigned short* pavg = (unsigned short*)(ws + 0);
    unsigned short* eavg = (unsigned short*)(ws + 4194304);
    unsigned short* wpb  = (unsigned short*)(ws + 8388608);
    unsigned short* web  = (unsigned short*)(ws + 12582912);
    unsigned short* peb  = (unsigned short*)(ws + 16777216);
    int* order  = (int*)(ws + 18874368);
    int* starts = order + NB;

    hipLaunchKernelGGL(k_avg,   dim3(2048),     dim3(256),  0, stream, prec, eff, pavg, eavg);
    hipLaunchKernelGGL(k_cvt,   dim3(4096),     dim3(256),  0, stream, Wp, We, wpb, web);
    hipLaunchKernelGGL(k_group, dim3(1),        dim3(1024), 0, stream, act, order, starts);
    hipLaunchKernelGGL(k_embed, dim3(8,16,2),   dim3(256),  0, stream,
                       pavg, eavg, wpb, web, bp, be, peb, out + 1048576);
    hipLaunchKernelGGL(k_trans, dim3(8,4,64),   dim3(256),  0, stream,
                       Wt, peb, order, starts, out);
}